// Round 1
// baseline (441.189 us; speedup 1.0000x reference)
//
#include <hip/hip_runtime.h>
#include <math.h>

typedef unsigned short u16;
typedef __attribute__((ext_vector_type(8))) short short8;
typedef __attribute__((ext_vector_type(4))) float f32x4;

#define MFMA16x16x32(a, b, c) __builtin_amdgcn_mfma_f32_16x16x32_bf16((a), (b), (c), 0, 0, 0)

__device__ __forceinline__ u16 f32_to_bf16(float x) {
  union { float f; unsigned u; } v; v.f = x;
  unsigned r = v.u + 0x7FFFu + ((v.u >> 16) & 1u);
  return (u16)(r >> 16);
}

// ---------------- fp32 -> bf16 convert ----------------
__global__ void cvt_f32_bf16(const float* __restrict__ in, u16* __restrict__ out, int n4) {
  int i = blockIdx.x * blockDim.x + threadIdx.x;
  int stride = gridDim.x * blockDim.x;
  for (; i < n4; i += stride) {
    float4 v = ((const float4*)in)[i];
    ushort4 o;
    o.x = f32_to_bf16(v.x);
    o.y = f32_to_bf16(v.y);
    o.z = f32_to_bf16(v.z);
    o.w = f32_to_bf16(v.w);
    ((ushort4*)out)[i] = o;
  }
}

// ---------------- bf16 NT GEMM: C = A(MxK) * B(NxK)^T + bias ----------------
// m97 structure: 128x128 tile, BK=32, 4 waves (2x2), global_load_lds width 16.
template <int OUT_BF16>
__global__ __launch_bounds__(256) void gemm_nt(
    const u16* __restrict__ A,      // M x K row-major bf16
    const u16* __restrict__ B,      // N x K row-major bf16
    const float* __restrict__ bias, // length N
    void* __restrict__ C,           // M x N (bf16 or f32)
    int M, int N, int K)
{
  __shared__ u16 As[128 * 32];
  __shared__ u16 Bs[128 * 32];
  const int tid = threadIdx.x;
  const int w = tid >> 6, l = tid & 63;
  const int l15 = l & 15, l4 = l >> 4;
  const int wm = w >> 1, wn = w & 1;
  const long bm = (long)blockIdx.y * 128, bn = (long)blockIdx.x * 128;

  const f32x4 z4 = {0.f, 0.f, 0.f, 0.f};
  f32x4 acc[4][4];
  #pragma unroll
  for (int m = 0; m < 4; ++m)
    #pragma unroll
    for (int n = 0; n < 4; ++n) acc[m][n] = z4;

  const int srow = l >> 2;        // 0..15 within a 16-row chunk
  const int scol = (l & 3) * 8;   // 0,8,16,24

  const int nkt = K >> 5;
  for (int kt = 0; kt < nkt; ++kt) {
    const int k0 = kt << 5;
    #pragma unroll
    for (int j = 0; j < 2; ++j) {
      const int rbase = w * 32 + j * 16;                  // wave-uniform
      const u16* ga = A + (bm + rbase + srow) * (long)K + k0 + scol;
      __builtin_amdgcn_global_load_lds(
          (const __attribute__((address_space(1))) void*)ga,
          (__attribute__((address_space(3))) void*)(As + rbase * 32), 16, 0, 0);
      const u16* gb = B + (bn + rbase + srow) * (long)K + k0 + scol;
      __builtin_amdgcn_global_load_lds(
          (const __attribute__((address_space(1))) void*)gb,
          (__attribute__((address_space(3))) void*)(Bs + rbase * 32), 16, 0, 0);
    }
    __syncthreads();
    short8 af[4], bf[4];
    #pragma unroll
    for (int m = 0; m < 4; ++m)
      af[m] = *(const short8*)(As + (wm * 64 + m * 16 + l15) * 32 + l4 * 8);
    #pragma unroll
    for (int n = 0; n < 4; ++n)
      bf[n] = *(const short8*)(Bs + (wn * 64 + n * 16 + l15) * 32 + l4 * 8);
    #pragma unroll
    for (int m = 0; m < 4; ++m)
      #pragma unroll
      for (int n = 0; n < 4; ++n)
        acc[m][n] = MFMA16x16x32(af[m], bf[n], acc[m][n]);
    __syncthreads();
  }

  #pragma unroll
  for (int m = 0; m < 4; ++m) {
    const long row0 = bm + wm * 64 + m * 16 + l4 * 4;
    #pragma unroll
    for (int n = 0; n < 4; ++n) {
      const long col = bn + wn * 64 + n * 16 + l15;
      const float bv = bias[col];
      #pragma unroll
      for (int r = 0; r < 4; ++r) {
        const float v = acc[m][n][r] + bv;
        if (OUT_BF16)
          ((u16*)C)[(row0 + r) * (long)N + col] = f32_to_bf16(v);
        else
          ((float*)C)[(row0 + r) * (long)N + col] = v;
      }
    }
  }
}

// ---------------- flash causal attention with alibi ----------------
// grid: (S/64, H, B); 4 waves; wave w owns q rows [qb0+16w, qb0+16w+16).
#define ATT_SCALE 0.08838834764831845f

__global__ __launch_bounds__(256) void attn_kernel(
    const u16* __restrict__ qkv,    // [B*S][6144] bf16 (q|k|v each h*128+d)
    const float* __restrict__ mask, // [16][2048] alibi bias
    u16* __restrict__ ctx)          // [B*S][2048] bf16
{
  const int S = 2048, NHD = 6144;
  const int qblk = blockIdx.x, h = blockIdx.y, b = blockIdx.z;
  const int tid = threadIdx.x;
  const int w = tid >> 6, l = tid & 63;
  const int l15 = l & 15, l4 = l >> 4;

  __shared__ u16 Ks[64 * 128];   // XOR-swizzled
  __shared__ u16 Vt[128 * 72];   // transposed V, pad 72, XOR-swizzled
  __shared__ u16 Ps[4][16 * 64]; // per-wave P, XOR-swizzled

  const int qb0 = qblk * 64;

  // Q fragments in registers (A-operand: row = l15, k = l4*8 + i, 4 chunks)
  short8 qf[4];
  {
    const int qrow = qb0 + w * 16 + l15;
    const u16* qp = qkv + (long)(b * S + qrow) * NHD + h * 128 + l4 * 8;
    #pragma unroll
    for (int kc = 0; kc < 4; ++kc)
      qf[kc] = *(const short8*)(qp + kc * 32);
  }

  const f32x4 z4 = {0.f, 0.f, 0.f, 0.f};
  f32x4 o[8];
  #pragma unroll
  for (int i = 0; i < 8; ++i) o[i] = z4;
  float m_r[4] = {-INFINITY, -INFINITY, -INFINITY, -INFINITY};
  float l_r[4] = {0.f, 0.f, 0.f, 0.f};

  const int srow = tid >> 4;       // 0..15
  const int scol = (tid & 15) * 8; // 0..120

  for (int kt = 0; kt <= qblk; ++kt) {
    // ---- stage K (swizzled) and V^T (padded + swizzled) ----
    #pragma unroll
    for (int p = 0; p < 4; ++p) {
      const int r0 = p * 16 + srow; // kv row 0..63
      const long grow = (long)(b * S + kt * 64 + r0) * NHD + h * 128 + scol;
      uint4 kv = *(const uint4*)(qkv + grow + 2048);
      int kbyte = (r0 * 128 + scol) * 2;
      kbyte ^= (r0 & 7) << 4;
      *(uint4*)((char*)Ks + kbyte) = kv;
      uint4 vv = *(const uint4*)(qkv + grow + 4096);
      const u16* ve = (const u16*)&vv;
      #pragma unroll
      for (int j = 0; j < 8; ++j) {
        const int d = scol + j;
        const int vbyte = ((d * 72 + r0) * 2) ^ (((d >> 3) & 7) << 4);
        *(u16*)((char*)Vt + vbyte) = ve[j];
      }
    }
    __syncthreads();

    // ---- QK^T: scores 16q x 64k per wave ----
    f32x4 sf[4];
    #pragma unroll
    for (int nt = 0; nt < 4; ++nt) sf[nt] = z4;
    #pragma unroll
    for (int nt = 0; nt < 4; ++nt) {
      const int krow = nt * 16 + l15;
      #pragma unroll
      for (int kc = 0; kc < 4; ++kc) {
        int kbyte = (krow * 128 + kc * 32 + l4 * 8) * 2;
        kbyte ^= (krow & 7) << 4;
        const short8 kf = *(const short8*)((const char*)Ks + kbyte);
        sf[nt] = MFMA16x16x32(qf[kc], kf, sf[nt]);
      }
    }

    // ---- online softmax (per reg r -> q row l4*4+r) ----
    float alpha[4];
    #pragma unroll
    for (int r = 0; r < 4; ++r) {
      const int qrow_l = l4 * 4 + r;
      const int qg = qb0 + w * 16 + qrow_l;
      float sc[4];
      float mx = -INFINITY;
      #pragma unroll
      for (int nt = 0; nt < 4; ++nt) {
        const int kg = kt * 64 + nt * 16 + l15;
        float s = sf[nt][r] * ATT_SCALE + mask[h * 2048 + kg];
        if (kg > qg) s = -INFINITY;
        sc[nt] = s;
        mx = fmaxf(mx, s);
      }
      #pragma unroll
      for (int d = 1; d < 16; d <<= 1)
        mx = fmaxf(mx, __shfl_xor(mx, d, 64));
      const float mnew = fmaxf(m_r[r], mx);
      float sum = 0.f;
      #pragma unroll
      for (int nt = 0; nt < 4; ++nt) {
        const float p = __expf(sc[nt] - mnew);
        sc[nt] = p;
        sum += p;
      }
      #pragma unroll
      for (int d = 1; d < 16; d <<= 1)
        sum += __shfl_xor(sum, d, 64);
      alpha[r] = __expf(m_r[r] - mnew);
      l_r[r] = l_r[r] * alpha[r] + sum;
      m_r[r] = mnew;
      // write P (bf16) to per-wave LDS, swizzled
      #pragma unroll
      for (int nt = 0; nt < 4; ++nt) {
        const int col = nt * 16 + l15;
        int pbyte = (qrow_l * 64 + col) * 2;
        pbyte ^= (qrow_l & 7) << 4;
        *(u16*)((char*)&Ps[w][0] + pbyte) = f32_to_bf16(sc[nt]);
      }
    }

    // ---- rescale O, then PV ----
    #pragma unroll
    for (int nt = 0; nt < 8; ++nt)
      #pragma unroll
      for (int r = 0; r < 4; ++r) o[nt][r] *= alpha[r];

    #pragma unroll
    for (int kc = 0; kc < 2; ++kc) {
      int pbyte = (l15 * 64 + kc * 32 + l4 * 8) * 2;
      pbyte ^= (l15 & 7) << 4;
      const short8 pf = *(const short8*)((const char*)&Ps[w][0] + pbyte);
      #pragma unroll
      for (int nt = 0; nt < 8; ++nt) {
        const int d = nt * 16 + l15;
        const int vbyte = ((d * 72 + kc * 32 + l4 * 8) * 2) ^ (((d >> 3) & 7) << 4);
        const short8 vf = *(const short8*)((const char*)Vt + vbyte);
        o[nt] = MFMA16x16x32(pf, vf, o[nt]);
      }
    }
    __syncthreads();
  }

  // ---- epilogue: normalize and write ctx ----
  #pragma unroll
  for (int nt = 0; nt < 8; ++nt) {
    #pragma unroll
    for (int r = 0; r < 4; ++r) {
      const int qg = qb0 + w * 16 + l4 * 4 + r;
      const float val = o[nt][r] / l_r[r];
      ctx[(long)(b * S + qg) * 2048 + h * 128 + nt * 16 + l15] = f32_to_bf16(val);
    }
  }
}

// ---------------- launch ----------------
extern "C" void kernel_launch(void* const* d_in, const int* in_sizes, int n_in,
                              void* d_out, int out_size, void* d_ws, size_t ws_size,
                              hipStream_t stream) {
  const float* x     = (const float*)d_in[0];
  const float* mask  = (const float*)d_in[1];
  const float* w_qkv = (const float*)d_in[2];
  const float* b_qkv = (const float*)d_in[3];
  const float* w_out = (const float*)d_in[4];
  const float* b_out = (const float*)d_in[5];
  float* out = (float*)d_out;

  // B=2, S=2048, D=2048, H=16, hd=128
  char* ws = (char*)d_ws;
  u16* xb    = (u16*)(ws);                     // 4096x2048   (16.8 MB)
  u16* wqkvb = (u16*)(ws + 16777216UL);        // 6144x2048   (25.2 MB)
  u16* woutb = (u16*)(ws + 41943040UL);        // 2048x2048   ( 8.4 MB)
  u16* qkvb  = (u16*)(ws + 50331648UL);        // 4096x6144   (50.3 MB)
  u16* ctxb  = (u16*)(ws + 100663296UL);       // 4096x2048   (16.8 MB) -> total 112 MB

  cvt_f32_bf16<<<2048, 256, 0, stream>>>(x, xb, 8388608 / 4);
  cvt_f32_bf16<<<2048, 256, 0, stream>>>(w_qkv, wqkvb, 12582912 / 4);
  cvt_f32_bf16<<<2048, 256, 0, stream>>>(w_out, woutb, 4194304 / 4);

  gemm_nt<1><<<dim3(48, 32), 256, 0, stream>>>(xb, wqkvb, b_qkv, (void*)qkvb, 4096, 6144, 2048);

  attn_kernel<<<dim3(32, 16, 2), 256, 0, stream>>>(qkvb, mask, ctxb);

  gemm_nt<0><<<dim3(16, 32), 256, 0, stream>>>(ctxb, woutb, b_out, (void*)out, 4096, 2048, 2048);
}

// Round 2
// 351.989 us; speedup vs baseline: 1.2534x; 1.2534x over previous
//
#include <hip/hip_runtime.h>
#include <math.h>

typedef unsigned short u16;
typedef __attribute__((ext_vector_type(8))) short short8;
typedef __attribute__((ext_vector_type(4))) float f32x4;

#define MFMA16x16x32(a, b, c) __builtin_amdgcn_mfma_f32_16x16x32_bf16((a), (b), (c), 0, 0, 0)

__device__ __forceinline__ u16 f32_to_bf16(float x) {
  union { float f; unsigned u; } v; v.f = x;
  unsigned r = v.u + 0x7FFFu + ((v.u >> 16) & 1u);
  return (u16)(r >> 16);
}

// ---------------- fp32 -> bf16 convert ----------------
__global__ void cvt_f32_bf16(const float* __restrict__ in, u16* __restrict__ out, int n4) {
  int i = blockIdx.x * blockDim.x + threadIdx.x;
  int stride = gridDim.x * blockDim.x;
  for (; i < n4; i += stride) {
    float4 v = ((const float4*)in)[i];
    ushort4 o;
    o.x = f32_to_bf16(v.x);
    o.y = f32_to_bf16(v.y);
    o.z = f32_to_bf16(v.z);
    o.w = f32_to_bf16(v.w);
    ((ushort4*)out)[i] = o;
  }
}

// ---------------- bf16 NT GEMM: C = A(MxK) * B(NxK)^T + bias ----------------
template <int OUT_BF16>
__global__ __launch_bounds__(256) void gemm_nt(
    const u16* __restrict__ A,      // M x K row-major bf16
    const u16* __restrict__ B,      // N x K row-major bf16
    const float* __restrict__ bias, // length N
    void* __restrict__ C,           // M x N (bf16 or f32)
    int M, int N, int K)
{
  __shared__ u16 As[128 * 32];
  __shared__ u16 Bs[128 * 32];
  const int tid = threadIdx.x;
  const int w = tid >> 6, l = tid & 63;
  const int l15 = l & 15, l4 = l >> 4;
  const int wm = w >> 1, wn = w & 1;
  const long bm = (long)blockIdx.y * 128, bn = (long)blockIdx.x * 128;

  const f32x4 z4 = {0.f, 0.f, 0.f, 0.f};
  f32x4 acc[4][4];
  #pragma unroll
  for (int m = 0; m < 4; ++m)
    #pragma unroll
    for (int n = 0; n < 4; ++n) acc[m][n] = z4;

  const int srow = l >> 2;        // 0..15 within a 16-row chunk
  const int scol = (l & 3) * 8;   // 0,8,16,24

  const int nkt = K >> 5;
  for (int kt = 0; kt < nkt; ++kt) {
    const int k0 = kt << 5;
    #pragma unroll
    for (int j = 0; j < 2; ++j) {
      const int rbase = w * 32 + j * 16;                  // wave-uniform
      const u16* ga = A + (bm + rbase + srow) * (long)K + k0 + scol;
      __builtin_amdgcn_global_load_lds(
          (const __attribute__((address_space(1))) void*)ga,
          (__attribute__((address_space(3))) void*)(As + rbase * 32), 16, 0, 0);
      const u16* gb = B + (bn + rbase + srow) * (long)K + k0 + scol;
      __builtin_amdgcn_global_load_lds(
          (const __attribute__((address_space(1))) void*)gb,
          (__attribute__((address_space(3))) void*)(Bs + rbase * 32), 16, 0, 0);
    }
    __syncthreads();
    short8 af[4], bf[4];
    #pragma unroll
    for (int m = 0; m < 4; ++m)
      af[m] = *(const short8*)(As + (wm * 64 + m * 16 + l15) * 32 + l4 * 8);
    #pragma unroll
    for (int n = 0; n < 4; ++n)
      bf[n] = *(const short8*)(Bs + (wn * 64 + n * 16 + l15) * 32 + l4 * 8);
    #pragma unroll
    for (int m = 0; m < 4; ++m)
      #pragma unroll
      for (int n = 0; n < 4; ++n)
        acc[m][n] = MFMA16x16x32(af[m], bf[n], acc[m][n]);
    __syncthreads();
  }

  #pragma unroll
  for (int m = 0; m < 4; ++m) {
    const long row0 = bm + wm * 64 + m * 16 + l4 * 4;
    #pragma unroll
    for (int n = 0; n < 4; ++n) {
      const long col = bn + wn * 64 + n * 16 + l15;
      const float bv = bias[col];
      #pragma unroll
      for (int r = 0; r < 4; ++r) {
        const float v = acc[m][n][r] + bv;
        if (OUT_BF16)
          ((u16*)C)[(row0 + r) * (long)N + col] = f32_to_bf16(v);
        else
          ((float*)C)[(row0 + r) * (long)N + col] = v;
      }
    }
  }
}

// ---------------- repack K and V into per-tile LDS images ----------------
// K image: K[r][d] at byte (r*256 + 2d) ^ ((r&7)<<4), r in [0,64), d in [0,128)
// V image: V[k][d] at byte (d*128 + 2k) ^ ((d&7)<<4), k in [0,64), d in [0,128)
__global__ __launch_bounds__(256) void repack_kv(
    const u16* __restrict__ qkv, u16* __restrict__ kimg, u16* __restrict__ vimg)
{
  const int t = blockIdx.x;  // kv tile 0..31
  const int h = blockIdx.y, b = blockIdx.z;
  const int tid = threadIdx.x;
  __shared__ u16 Vl[64][136];  // pad 8 -> 16B-aligned rows

  const long qbase = ((long)(b * 2048 + t * 64)) * 6144 + h * 128;
  u16* kout = kimg + (((long)(b * 16 + h) * 32 + t) * 8192);
  u16* vout = vimg + (((long)(b * 16 + h) * 32 + t) * 8192);

  #pragma unroll
  for (int i = 0; i < 4; ++i) {
    const int j = tid + i * 256;
    {  // stage V tile linear into LDS
      const int r = j >> 4, c8 = (j & 15) * 8;
      uint4 v = *(const uint4*)(qkv + qbase + (long)r * 6144 + 4096 + c8);
      *(uint4*)(&Vl[r][c8]) = v;
    }
    {  // K repack: direct global->global
      const int byte = j * 16;
      const int r = byte >> 8;
      const int wv = (byte & 255) ^ ((r & 7) << 4);
      const int d0 = wv >> 1;
      uint4 v = *(const uint4*)(qkv + qbase + (long)r * 6144 + 2048 + d0);
      *(uint4*)(kout + j * 8) = v;
    }
  }
  __syncthreads();
  #pragma unroll
  for (int i = 0; i < 4; ++i) {
    const int j = tid + i * 256;
    const int byte = j * 16;
    const int d = byte >> 7;
    const int wv = (byte & 127) ^ ((d & 7) << 4);
    const int k0 = wv >> 1;
    u16 tmp[8];
    #pragma unroll
    for (int m = 0; m < 8; ++m) tmp[m] = Vl[k0 + m][d];
    *(uint4*)(vout + j * 8) = *(const uint4*)tmp;
  }
}

// ---------------- flash causal attention with alibi ----------------
// grid: (16, H, B): block p handles q-blocks p and 31-p (balanced: 33 tiles).
__global__ __launch_bounds__(256) void attn_kernel(
    const u16* __restrict__ qkv,   // [B*S][6144] bf16
    const u16* __restrict__ kimg,  // [B][H][32][8192] tile images
    const u16* __restrict__ vimg,
    u16* __restrict__ ctx)         // [B*S][2048] bf16
{
  const int S = 2048, NHD = 6144, NT = 32;
  const int p = blockIdx.x, h = blockIdx.y, b = blockIdx.z;
  const int tid = threadIdx.x;
  const int w = tid >> 6, l = tid & 63;
  const int l15 = l & 15, l4 = l >> 4;

  __shared__ u16 Ks[64 * 128];
  __shared__ u16 Vt[128 * 64];
  __shared__ u16 Ps[4][16 * 64];

  const float LOG2E = 1.44269504088896f;
  const float c1 = 0.08838834764831845f * LOG2E;
  const float slope2 = exp2f(-0.5f * (float)(h + 1)) * LOG2E;

  const f32x4 z4 = {0.f, 0.f, 0.f, 0.f};

  for (int pass = 0; pass < 2; ++pass) {
    const int qblk = pass ? (NT - 1 - p) : p;
    const int qb0 = qblk * 64;

    short8 qf[4];
    {
      const int qrow = qb0 + w * 16 + l15;
      const u16* qp = qkv + (long)(b * S + qrow) * NHD + h * 128 + l4 * 8;
      #pragma unroll
      for (int kc = 0; kc < 4; ++kc) qf[kc] = *(const short8*)(qp + kc * 32);
    }

    f32x4 o[8];
    #pragma unroll
    for (int i = 0; i < 8; ++i) o[i] = z4;
    float m_r[4] = {-3.0e38f, -3.0e38f, -3.0e38f, -3.0e38f};
    float l_r[4] = {0.f, 0.f, 0.f, 0.f};

    for (int kt = 0; kt <= qblk; ++kt) {
      // ---- stage K and V^T tile images (linear copies) ----
      const u16* ksrc = kimg + (((long)(b * 16 + h) * NT + kt) * 8192);
      const u16* vsrc = vimg + (((long)(b * 16 + h) * NT + kt) * 8192);
      #pragma unroll
      for (int i = 0; i < 4; ++i) {
        const int chunk = w * 4 + i;  // wave-uniform, 1KB each
        __builtin_amdgcn_global_load_lds(
            (const __attribute__((address_space(1))) void*)(ksrc + chunk * 512 + l * 8),
            (__attribute__((address_space(3))) void*)(Ks + chunk * 512), 16, 0, 0);
        __builtin_amdgcn_global_load_lds(
            (const __attribute__((address_space(1))) void*)(vsrc + chunk * 512 + l * 8),
            (__attribute__((address_space(3))) void*)(Vt + chunk * 512), 16, 0, 0);
      }
      __syncthreads();

      // ---- QK^T: 16q x 64k per wave ----
      f32x4 sf[4];
      #pragma unroll
      for (int nt = 0; nt < 4; ++nt) sf[nt] = z4;
      #pragma unroll
      for (int nt = 0; nt < 4; ++nt) {
        const int krow = nt * 16 + l15;
        #pragma unroll
        for (int kc = 0; kc < 4; ++kc) {
          int kbyte = (krow * 256 + kc * 64 + l4 * 16) ^ ((krow & 7) << 4);
          const short8 kf = *(const short8*)((const char*)Ks + kbyte);
          sf[nt] = MFMA16x16x32(qf[kc], kf, sf[nt]);
        }
      }

      // ---- online softmax (base-2 domain, inline alibi) ----
      float add_nt[4];
      int kg_nt[4];
      #pragma unroll
      for (int nt = 0; nt < 4; ++nt) {
        kg_nt[nt] = kt * 64 + nt * 16 + l15;
        add_nt[nt] = slope2 * (float)(kg_nt[nt] - (S - 1));
      }
      const bool diag = (kt == qblk);
      float alpha[4];
      #pragma unroll
      for (int r = 0; r < 4; ++r) {
        const int qrow_l = l4 * 4 + r;
        const int qg = qb0 + w * 16 + qrow_l;
        float sc[4];
        #pragma unroll
        for (int nt = 0; nt < 4; ++nt) sc[nt] = sf[nt][r] * c1 + add_nt[nt];
        if (diag) {
          #pragma unroll
          for (int nt = 0; nt < 4; ++nt)
            if (kg_nt[nt] > qg) sc[nt] = -3.0e38f;
        }
        float mx = fmaxf(fmaxf(sc[0], sc[1]), fmaxf(sc[2], sc[3]));
        #pragma unroll
        for (int d = 1; d < 16; d <<= 1) mx = fmaxf(mx, __shfl_xor(mx, d, 64));
        const float mnew = fmaxf(m_r[r], mx);
        float sum = 0.f;
        #pragma unroll
        for (int nt = 0; nt < 4; ++nt) {
          const float pv = exp2f(sc[nt] - mnew);
          sc[nt] = pv;
          sum += pv;
        }
        #pragma unroll
        for (int d = 1; d < 16; d <<= 1) sum += __shfl_xor(sum, d, 64);
        alpha[r] = exp2f(m_r[r] - mnew);
        l_r[r] = l_r[r] * alpha[r] + sum;
        m_r[r] = mnew;
        #pragma unroll
        for (int nt = 0; nt < 4; ++nt) {
          int pbyte = ((qrow_l * 64 + nt * 16 + l15) * 2) ^ ((qrow_l & 7) << 4);
          *(u16*)((char*)&Ps[w][0] + pbyte) = f32_to_bf16(sc[nt]);
        }
      }

      // ---- rescale O, then PV ----
      #pragma unroll
      for (int nt = 0; nt < 8; ++nt)
        #pragma unroll
        for (int r = 0; r < 4; ++r) o[nt][r] *= alpha[r];

      #pragma unroll
      for (int kc = 0; kc < 2; ++kc) {
        int pbyte = ((l15 * 64 + kc * 32 + l4 * 8) * 2) ^ ((l15 & 7) << 4);
        const short8 pf = *(const short8*)((const char*)&Ps[w][0] + pbyte);
        #pragma unroll
        for (int nt = 0; nt < 8; ++nt) {
          const int d = nt * 16 + l15;
          const int vbyte = ((d * 128 + kc * 64 + l4 * 16)) ^ ((d & 7) << 4);
          const short8 vf = *(const short8*)((const char*)Vt + vbyte);
          o[nt] = MFMA16x16x32(pf, vf, o[nt]);
        }
      }
      __syncthreads();
    }

    // ---- epilogue ----
    float rl[4];
    #pragma unroll
    for (int r = 0; r < 4; ++r) rl[r] = 1.0f / l_r[r];
    #pragma unroll
    for (int nt = 0; nt < 8; ++nt) {
      #pragma unroll
      for (int r = 0; r < 4; ++r) {
        const int qg = qb0 + w * 16 + l4 * 4 + r;
        ctx[(long)(b * S + qg) * 2048 + h * 128 + nt * 16 + l15] =
            f32_to_bf16(o[nt][r] * rl[r]);
      }
    }
  }
}

// ---------------- launch ----------------
extern "C" void kernel_launch(void* const* d_in, const int* in_sizes, int n_in,
                              void* d_out, int out_size, void* d_ws, size_t ws_size,
                              hipStream_t stream) {
  const float* x     = (const float*)d_in[0];
  const float* w_qkv = (const float*)d_in[2];
  const float* b_qkv = (const float*)d_in[3];
  const float* w_out = (const float*)d_in[4];
  const float* b_out = (const float*)d_in[5];
  float* out = (float*)d_out;

  // B=2, S=2048, D=2048, H=16, hd=128
  char* ws = (char*)d_ws;
  u16* xb    = (u16*)(ws);                     // 4096x2048   (16.8 MB) dead after GEMM1
  u16* wqkvb = (u16*)(ws + 16777216UL);        // 6144x2048   (25.2 MB) dead after GEMM1
  u16* woutb = (u16*)(ws + 41943040UL);        // 2048x2048   ( 8.4 MB)
  u16* qkvb  = (u16*)(ws + 50331648UL);        // 4096x6144   (50.3 MB)
  u16* ctxb  = (u16*)(ws + 100663296UL);       // 4096x2048   (16.8 MB)
  u16* kimg  = (u16*)(ws);                     // 16.8 MB (overlays xb)
  u16* vimg  = (u16*)(ws + 16777216UL);        // 16.8 MB (overlays wqkvb)

  cvt_f32_bf16<<<2048, 256, 0, stream>>>(x, xb, 8388608 / 4);
  cvt_f32_bf16<<<2048, 256, 0, stream>>>(w_qkv, wqkvb, 12582912 / 4);
  cvt_f32_bf16<<<2048, 256, 0, stream>>>(w_out, woutb, 4194304 / 4);

  gemm_nt<1><<<dim3(48, 32), 256, 0, stream>>>(xb, wqkvb, b_qkv, (void*)qkvb, 4096, 6144, 2048);

  repack_kv<<<dim3(32, 16, 2), 256, 0, stream>>>(qkvb, kimg, vimg);

  attn_kernel<<<dim3(16, 16, 2), 256, 0, stream>>>(qkvb, kimg, vimg, ctxb);

  gemm_nt<0><<<dim3(16, 32), 256, 0, stream>>>(ctxb, woutb, b_out, (void*)out, 4096, 2048, 2048);
}

// Round 3
// 310.049 us; speedup vs baseline: 1.4230x; 1.1353x over previous
//
#include <hip/hip_runtime.h>
#include <math.h>

typedef unsigned short u16;
typedef __attribute__((ext_vector_type(8))) short short8;
typedef __attribute__((ext_vector_type(4))) float f32x4;

#define MFMA16x16x32(a, b, c) __builtin_amdgcn_mfma_f32_16x16x32_bf16((a), (b), (c), 0, 0, 0)
#define GLL16(g, s)                                                        \
  __builtin_amdgcn_global_load_lds(                                        \
      (const __attribute__((address_space(1))) void*)(g),                  \
      (__attribute__((address_space(3))) void*)(s), 16, 0, 0)

__device__ __forceinline__ u16 f32_to_bf16(float x) {
  union { float f; unsigned u; } v; v.f = x;
  unsigned r = v.u + 0x7FFFu + ((v.u >> 16) & 1u);
  return (u16)(r >> 16);
}

// ---------------- fp32 -> bf16 convert ----------------
__global__ void cvt_f32_bf16(const float* __restrict__ in, u16* __restrict__ out, int n4) {
  int i = blockIdx.x * blockDim.x + threadIdx.x;
  int stride = gridDim.x * blockDim.x;
  for (; i < n4; i += stride) {
    float4 v = ((const float4*)in)[i];
    ushort4 o;
    o.x = f32_to_bf16(v.x);
    o.y = f32_to_bf16(v.y);
    o.z = f32_to_bf16(v.z);
    o.w = f32_to_bf16(v.w);
    ((ushort4*)out)[i] = o;
  }
}

// ---------------- 8-phase bf16 NT GEMM: C = A(MxK)*B(NxK)^T + bias ----------------
// Tile 128x256, BK=64, 8 waves (2M x 4N), per-wave 64x64.
// LDS XOR-swizzle ((row&7)<<4) via pre-inverse-swizzled global source.
// Counted vmcnt(6) + raw s_barrier per phase; drain 2->0 only on last tile.
template <int OUT_BF16>
__global__ __launch_bounds__(512, 2) void gemm_nt_8p(
    const u16* __restrict__ A,      // M x K row-major bf16
    const u16* __restrict__ B,      // N x K row-major bf16
    const float* __restrict__ bias, // length N
    void* __restrict__ C,           // M x N (bf16 or f32)
    int M, int N, int K)
{
  __shared__ u16 As[2][8192];    // [buf][128 rows x 64 cols] swizzled
  __shared__ u16 Bs[2][16384];   // [buf][2 halves x 128 x 64] swizzled

  const int tid = threadIdx.x;
  const int w = tid >> 6, l = tid & 63;
  const int l15 = l & 15, l4 = l >> 4;
  const int wm = w >> 2, wn = w & 3;
  const long bm = (long)blockIdx.y * 128, bn = (long)blockIdx.x * 256;
  const int NT = K >> 6;

  // staging sources (inverse-swizzled): LDS byte q holds global col (q&127)^((row&7)<<4)
  const u16 *aSrc0, *aSrc1, *bSrc0, *bSrc1;
  {
    int q = w * 2048 + l * 16;
    int r = q >> 7, cb = (q & 127) ^ ((r & 7) << 4);
    aSrc0 = A + (bm + r) * (long)K + (cb >> 1);
    bSrc0 = B + (bn + r) * (long)K + (cb >> 1);
    q += 1024;
    r = q >> 7; cb = (q & 127) ^ ((r & 7) << 4);
    aSrc1 = A + (bm + r) * (long)K + (cb >> 1);
    bSrc1 = B + (bn + r) * (long)K + (cb >> 1);
  }
  const long bHS = 128 * (long)K;   // B half-1 row offset
  const int ldsA = w * 1024;        // u16 units: wave-uniform stage dest

  const f32x4 z4 = {0.f, 0.f, 0.f, 0.f};
  f32x4 acc[4][4];
  #pragma unroll
  for (int m = 0; m < 4; ++m)
    #pragma unroll
    for (int n = 0; n < 4; ++n) acc[m][n] = z4;

  // read offsets: byte within 128B row, swizzled; per-lane constant
  const int xo0 = (l4 * 16) ^ ((l15 & 7) << 4);
  const int xo1 = (64 + l4 * 16) ^ ((l15 & 7) << 4);
  const char* aRd = (const char*)&As[0][0] + (wm * 64 + l15) * 128;
  const char* bRd = (const char*)&Bs[0][0] + (wn * 32 + l15) * 128;

  // prologue: issue A(0), Bh0(0), Bh1(0)  [6 loads]
  GLL16(aSrc0, &As[0][ldsA]);
  GLL16(aSrc1, &As[0][ldsA + 512]);
  GLL16(bSrc0, &Bs[0][ldsA]);
  GLL16(bSrc1, &Bs[0][ldsA + 512]);
  GLL16(bSrc0 + bHS, &Bs[0][8192 + ldsA]);
  GLL16(bSrc1 + bHS, &Bs[0][8192 + ldsA + 512]);

  short8 af[4][2], bf[4][2];

  for (int t = 0; t < NT; ++t) {
    const int nxt = t + 1;
    const int bufo = t & 1;

    // ---- phase 0: stage A(t+1)+Bh0(t+1); compute n-cols 0..1 ----
    if (nxt < NT) {
      const long ko = (long)nxt * 64;
      const int nb = nxt & 1;
      GLL16(aSrc0 + ko, &As[nb][ldsA]);
      GLL16(aSrc1 + ko, &As[nb][ldsA + 512]);
      GLL16(bSrc0 + ko, &Bs[nb][ldsA]);
      GLL16(bSrc1 + ko, &Bs[nb][ldsA + 512]);
      asm volatile("s_waitcnt vmcnt(6)\ns_barrier" ::: "memory");
    } else {
      asm volatile("s_waitcnt vmcnt(2)\ns_barrier" ::: "memory");
    }
    const char* ab = aRd + bufo * 16384;
    const char* bb = bRd + bufo * 32768;
    #pragma unroll
    for (int m = 0; m < 4; ++m) {
      af[m][0] = *(const short8*)(ab + m * 2048 + xo0);
      af[m][1] = *(const short8*)(ab + m * 2048 + xo1);
    }
    #pragma unroll
    for (int n = 0; n < 2; ++n) {
      bf[n][0] = *(const short8*)(bb + n * 2048 + xo0);
      bf[n][1] = *(const short8*)(bb + n * 2048 + xo1);
    }
    __builtin_amdgcn_s_setprio(1);
    #pragma unroll
    for (int m = 0; m < 4; ++m)
      #pragma unroll
      for (int n = 0; n < 2; ++n) {
        acc[m][n] = MFMA16x16x32(af[m][0], bf[n][0], acc[m][n]);
        acc[m][n] = MFMA16x16x32(af[m][1], bf[n][1], acc[m][n]);
      }
    __builtin_amdgcn_s_setprio(0);

    // ---- phase 1: stage Bh1(t+1); compute n-cols 2..3 ----
    if (nxt < NT) {
      const long ko = (long)nxt * 64;
      const int nb = nxt & 1;
      GLL16(bSrc0 + bHS + ko, &Bs[nb][8192 + ldsA]);
      GLL16(bSrc1 + bHS + ko, &Bs[nb][8192 + ldsA + 512]);
      asm volatile("s_waitcnt vmcnt(6)\ns_barrier" ::: "memory");
    } else {
      asm volatile("s_waitcnt vmcnt(0)\ns_barrier" ::: "memory");
    }
    const char* bb1 = bb + 16384;
    #pragma unroll
    for (int n = 0; n < 2; ++n) {
      bf[2 + n][0] = *(const short8*)(bb1 + n * 2048 + xo0);
      bf[2 + n][1] = *(const short8*)(bb1 + n * 2048 + xo1);
    }
    __builtin_amdgcn_s_setprio(1);
    #pragma unroll
    for (int m = 0; m < 4; ++m)
      #pragma unroll
      for (int n = 2; n < 4; ++n) {
        acc[m][n] = MFMA16x16x32(af[m][0], bf[n][0], acc[m][n]);
        acc[m][n] = MFMA16x16x32(af[m][1], bf[n][1], acc[m][n]);
      }
    __builtin_amdgcn_s_setprio(0);
  }

  // ---- epilogue ----
  #pragma unroll
  for (int m = 0; m < 4; ++m) {
    const long row0 = bm + wm * 64 + m * 16 + l4 * 4;
    #pragma unroll
    for (int n = 0; n < 4; ++n) {
      const long col = bn + wn * 32 + (n & 1) * 16 + (n >> 1) * 128 + l15;
      const float bv = bias[col];
      #pragma unroll
      for (int r = 0; r < 4; ++r) {
        const float v = acc[m][n][r] + bv;
        if (OUT_BF16)
          ((u16*)C)[(row0 + r) * (long)N + col] = f32_to_bf16(v);
        else
          ((float*)C)[(row0 + r) * (long)N + col] = v;
      }
    }
  }
}

// ---------------- repack K and V into per-tile LDS images ----------------
__global__ __launch_bounds__(256) void repack_kv(
    const u16* __restrict__ qkv, u16* __restrict__ kimg, u16* __restrict__ vimg)
{
  const int t = blockIdx.x;  // kv tile 0..31
  const int h = blockIdx.y, b = blockIdx.z;
  const int tid = threadIdx.x;
  __shared__ u16 Vl[64][136];

  const long qbase = ((long)(b * 2048 + t * 64)) * 6144 + h * 128;
  u16* kout = kimg + (((long)(b * 16 + h) * 32 + t) * 8192);
  u16* vout = vimg + (((long)(b * 16 + h) * 32 + t) * 8192);

  #pragma unroll
  for (int i = 0; i < 4; ++i) {
    const int j = tid + i * 256;
    {
      const int r = j >> 4, c8 = (j & 15) * 8;
      uint4 v = *(const uint4*)(qkv + qbase + (long)r * 6144 + 4096 + c8);
      *(uint4*)(&Vl[r][c8]) = v;
    }
    {
      const int byte = j * 16;
      const int r = byte >> 8;
      const int wv = (byte & 255) ^ ((r & 7) << 4);
      const int d0 = wv >> 1;
      uint4 v = *(const uint4*)(qkv + qbase + (long)r * 6144 + 2048 + d0);
      *(uint4*)(kout + j * 8) = v;
    }
  }
  __syncthreads();
  #pragma unroll
  for (int i = 0; i < 4; ++i) {
    const int j = tid + i * 256;
    const int byte = j * 16;
    const int d = byte >> 7;
    const int wv = (byte & 127) ^ ((d & 7) << 4);
    const int k0 = wv >> 1;
    u16 tmp[8];
    #pragma unroll
    for (int m = 0; m < 8; ++m) tmp[m] = Vl[k0 + m][d];
    *(uint4*)(vout + j * 8) = *(const uint4*)tmp;
  }
}

// ---------------- flash causal attention with alibi ----------------
__global__ __launch_bounds__(256) void attn_kernel(
    const u16* __restrict__ qkv,   // [B*S][6144] bf16
    const u16* __restrict__ kimg,  // [B][H][32][8192] tile images
    const u16* __restrict__ vimg,
    u16* __restrict__ ctx)         // [B*S][2048] bf16
{
  const int S = 2048, NHD = 6144, NT = 32;
  const int p = blockIdx.x, h = blockIdx.y, b = blockIdx.z;
  const int tid = threadIdx.x;
  const int w = tid >> 6, l = tid & 63;
  const int l15 = l & 15, l4 = l >> 4;

  __shared__ u16 Ks[64 * 128];
  __shared__ u16 Vt[128 * 64];
  __shared__ u16 Ps[4][16 * 64];

  const float LOG2E = 1.44269504088896f;
  const float c1 = 0.08838834764831845f * LOG2E;
  const float slope2 = exp2f(-0.5f * (float)(h + 1)) * LOG2E;

  const f32x4 z4 = {0.f, 0.f, 0.f, 0.f};

  for (int pass = 0; pass < 2; ++pass) {
    const int qblk = pass ? (NT - 1 - p) : p;
    const int qb0 = qblk * 64;

    short8 qf[4];
    {
      const int qrow = qb0 + w * 16 + l15;
      const u16* qp = qkv + (long)(b * S + qrow) * NHD + h * 128 + l4 * 8;
      #pragma unroll
      for (int kc = 0; kc < 4; ++kc) qf[kc] = *(const short8*)(qp + kc * 32);
    }

    f32x4 o[8];
    #pragma unroll
    for (int i = 0; i < 8; ++i) o[i] = z4;
    float m_r[4] = {-3.0e38f, -3.0e38f, -3.0e38f, -3.0e38f};
    float l_r[4] = {0.f, 0.f, 0.f, 0.f};

    for (int kt = 0; kt <= qblk; ++kt) {
      const u16* ksrc = kimg + (((long)(b * 16 + h) * NT + kt) * 8192);
      const u16* vsrc = vimg + (((long)(b * 16 + h) * NT + kt) * 8192);
      #pragma unroll
      for (int i = 0; i < 4; ++i) {
        const int chunk = w * 4 + i;
        __builtin_amdgcn_global_load_lds(
            (const __attribute__((address_space(1))) void*)(ksrc + chunk * 512 + l * 8),
            (__attribute__((address_space(3))) void*)(Ks + chunk * 512), 16, 0, 0);
        __builtin_amdgcn_global_load_lds(
            (const __attribute__((address_space(1))) void*)(vsrc + chunk * 512 + l * 8),
            (__attribute__((address_space(3))) void*)(Vt + chunk * 512), 16, 0, 0);
      }
      __syncthreads();

      f32x4 sf[4];
      #pragma unroll
      for (int nt = 0; nt < 4; ++nt) sf[nt] = z4;
      #pragma unroll
      for (int nt = 0; nt < 4; ++nt) {
        const int krow = nt * 16 + l15;
        #pragma unroll
        for (int kc = 0; kc < 4; ++kc) {
          int kbyte = (krow * 256 + kc * 64 + l4 * 16) ^ ((krow & 7) << 4);
          const short8 kf = *(const short8*)((const char*)Ks + kbyte);
          sf[nt] = MFMA16x16x32(qf[kc], kf, sf[nt]);
        }
      }

      float add_nt[4];
      int kg_nt[4];
      #pragma unroll
      for (int nt = 0; nt < 4; ++nt) {
        kg_nt[nt] = kt * 64 + nt * 16 + l15;
        add_nt[nt] = slope2 * (float)(kg_nt[nt] - (S - 1));
      }
      const bool diag = (kt == qblk);
      float alpha[4];
      #pragma unroll
      for (int r = 0; r < 4; ++r) {
        const int qrow_l = l4 * 4 + r;
        const int qg = qb0 + w * 16 + qrow_l;
        float sc[4];
        #pragma unroll
        for (int nt = 0; nt < 4; ++nt) sc[nt] = sf[nt][r] * c1 + add_nt[nt];
        if (diag) {
          #pragma unroll
          for (int nt = 0; nt < 4; ++nt)
            if (kg_nt[nt] > qg) sc[nt] = -3.0e38f;
        }
        float mx = fmaxf(fmaxf(sc[0], sc[1]), fmaxf(sc[2], sc[3]));
        #pragma unroll
        for (int d = 1; d < 16; d <<= 1) mx = fmaxf(mx, __shfl_xor(mx, d, 64));
        const float mnew = fmaxf(m_r[r], mx);
        float sum = 0.f;
        #pragma unroll
        for (int nt = 0; nt < 4; ++nt) {
          const float pv = exp2f(sc[nt] - mnew);
          sc[nt] = pv;
          sum += pv;
        }
        #pragma unroll
        for (int d = 1; d < 16; d <<= 1) sum += __shfl_xor(sum, d, 64);
        alpha[r] = exp2f(m_r[r] - mnew);
        l_r[r] = l_r[r] * alpha[r] + sum;
        m_r[r] = mnew;
        #pragma unroll
        for (int nt = 0; nt < 4; ++nt) {
          int pbyte = ((qrow_l * 64 + nt * 16 + l15) * 2) ^ ((qrow_l & 7) << 4);
          *(u16*)((char*)&Ps[w][0] + pbyte) = f32_to_bf16(sc[nt]);
        }
      }

      #pragma unroll
      for (int nt = 0; nt < 8; ++nt)
        #pragma unroll
        for (int r = 0; r < 4; ++r) o[nt][r] *= alpha[r];

      #pragma unroll
      for (int kc = 0; kc < 2; ++kc) {
        int pbyte = ((l15 * 64 + kc * 32 + l4 * 8) * 2) ^ ((l15 & 7) << 4);
        const short8 pf = *(const short8*)((const char*)&Ps[w][0] + pbyte);
        #pragma unroll
        for (int nt = 0; nt < 8; ++nt) {
          const int d = nt * 16 + l15;
          const int vbyte = ((d * 128 + kc * 64 + l4 * 16)) ^ ((d & 7) << 4);
          const short8 vf = *(const short8*)((const char*)Vt + vbyte);
          o[nt] = MFMA16x16x32(pf, vf, o[nt]);
        }
      }
      __syncthreads();
    }

    float rl[4];
    #pragma unroll
    for (int r = 0; r < 4; ++r) rl[r] = 1.0f / l_r[r];
    #pragma unroll
    for (int nt = 0; nt < 8; ++nt) {
      #pragma unroll
      for (int r = 0; r < 4; ++r) {
        const int qg = qb0 + w * 16 + l4 * 4 + r;
        ctx[(long)(b * S + qg) * 2048 + h * 128 + nt * 16 + l15] =
            f32_to_bf16(o[nt][r] * rl[r]);
      }
    }
  }
}

// ---------------- launch ----------------
extern "C" void kernel_launch(void* const* d_in, const int* in_sizes, int n_in,
                              void* d_out, int out_size, void* d_ws, size_t ws_size,
                              hipStream_t stream) {
  const float* x     = (const float*)d_in[0];
  const float* w_qkv = (const float*)d_in[2];
  const float* b_qkv = (const float*)d_in[3];
  const float* w_out = (const float*)d_in[4];
  const float* b_out = (const float*)d_in[5];
  float* out = (float*)d_out;

  // B=2, S=2048, D=2048, H=16, hd=128
  char* ws = (char*)d_ws;
  u16* xb    = (u16*)(ws);                     // 4096x2048   (16.8 MB) dead after GEMM1
  u16* wqkvb = (u16*)(ws + 16777216UL);        // 6144x2048   (25.2 MB) dead after GEMM1
  u16* woutb = (u16*)(ws + 41943040UL);        // 2048x2048   ( 8.4 MB)
  u16* qkvb  = (u16*)(ws + 50331648UL);        // 4096x6144   (50.3 MB)
  u16* ctxb  = (u16*)(ws + 100663296UL);       // 4096x2048   (16.8 MB)
  u16* kimg  = (u16*)(ws);                     // 16.8 MB (overlays xb)
  u16* vimg  = (u16*)(ws + 16777216UL);        // 16.8 MB (overlays wqkvb)

  cvt_f32_bf16<<<2048, 256, 0, stream>>>(x, xb, 8388608 / 4);
  cvt_f32_bf16<<<2048, 256, 0, stream>>>(w_qkv, wqkvb, 12582912 / 4);
  cvt_f32_bf16<<<2048, 256, 0, stream>>>(w_out, woutb, 4194304 / 4);

  gemm_nt_8p<1><<<dim3(24, 32), 512, 0, stream>>>(xb, wqkvb, b_qkv, (void*)qkvb, 4096, 6144, 2048);

  repack_kv<<<dim3(32, 16, 2), 256, 0, stream>>>(qkvb, kimg, vimg);

  attn_kernel<<<dim3(16, 16, 2), 256, 0, stream>>>(qkvb, kimg, vimg, ctxb);

  gemm_nt_8p<0><<<dim3(8, 32), 512, 0, stream>>>(ctxb, woutb, b_out, (void*)out, 4096, 2048, 2048);
}

// Round 4
// 309.698 us; speedup vs baseline: 1.4246x; 1.0011x over previous
//
#include <hip/hip_runtime.h>
#include <math.h>

typedef unsigned short u16;
typedef __attribute__((ext_vector_type(8))) short short8;
typedef __attribute__((ext_vector_type(4))) float f32x4;

#define MFMA16x16x32(a, b, c) __builtin_amdgcn_mfma_f32_16x16x32_bf16((a), (b), (c), 0, 0, 0)
#define GLL16(g, s)                                                        \
  __builtin_amdgcn_global_load_lds(                                        \
      (const __attribute__((address_space(1))) void*)(g),                  \
      (__attribute__((address_space(3))) void*)(s), 16, 0, 0)

__device__ __forceinline__ u16 f32_to_bf16(float x) {
  union { float f; unsigned u; } v; v.f = x;
  unsigned r = v.u + 0x7FFFu + ((v.u >> 16) & 1u);
  return (u16)(r >> 16);
}

// ---------------- fp32 -> bf16 convert ----------------
__global__ void cvt_f32_bf16(const float* __restrict__ in, u16* __restrict__ out, int n4) {
  int i = blockIdx.x * blockDim.x + threadIdx.x;
  int stride = gridDim.x * blockDim.x;
  for (; i < n4; i += stride) {
    float4 v = ((const float4*)in)[i];
    ushort4 o;
    o.x = f32_to_bf16(v.x);
    o.y = f32_to_bf16(v.y);
    o.z = f32_to_bf16(v.z);
    o.w = f32_to_bf16(v.w);
    ((ushort4*)out)[i] = o;
  }
}

// ---------------- 8-phase bf16 NT GEMM: C = A(MxK)*B(NxK)^T + bias ----------------
// Tile 128x256, BK=64, 8 waves (2M x 4N), per-wave 64x64.
// LDS XOR-swizzle ((row&7)<<4) via pre-inverse-swizzled global source.
// Counted vmcnt(6) + raw s_barrier per phase; drain 2->0 only on last tile.
template <int OUT_BF16>
__global__ __launch_bounds__(512, 2) void gemm_nt_8p(
    const u16* __restrict__ A,      // M x K row-major bf16
    const u16* __restrict__ B,      // N x K row-major bf16
    const float* __restrict__ bias, // length N
    void* __restrict__ C,           // M x N (bf16 or f32)
    int M, int N, int K)
{
  __shared__ u16 As[2][8192];    // [buf][128 rows x 64 cols] swizzled
  __shared__ u16 Bs[2][16384];   // [buf][2 halves x 128 x 64] swizzled

  const int tid = threadIdx.x;
  const int w = tid >> 6, l = tid & 63;
  const int l15 = l & 15, l4 = l >> 4;
  const int wm = w >> 2, wn = w & 3;
  const long bm = (long)blockIdx.y * 128, bn = (long)blockIdx.x * 256;
  const int NT = K >> 6;

  // staging sources (inverse-swizzled): LDS byte q holds global col (q&127)^((row&7)<<4)
  const u16 *aSrc0, *aSrc1, *bSrc0, *bSrc1;
  {
    int q = w * 2048 + l * 16;
    int r = q >> 7, cb = (q & 127) ^ ((r & 7) << 4);
    aSrc0 = A + (bm + r) * (long)K + (cb >> 1);
    bSrc0 = B + (bn + r) * (long)K + (cb >> 1);
    q += 1024;
    r = q >> 7; cb = (q & 127) ^ ((r & 7) << 4);
    aSrc1 = A + (bm + r) * (long)K + (cb >> 1);
    bSrc1 = B + (bn + r) * (long)K + (cb >> 1);
  }
  const long bHS = 128 * (long)K;   // B half-1 row offset
  const int ldsA = w * 1024;        // u16 units: wave-uniform stage dest

  const f32x4 z4 = {0.f, 0.f, 0.f, 0.f};
  f32x4 acc[4][4];
  #pragma unroll
  for (int m = 0; m < 4; ++m)
    #pragma unroll
    for (int n = 0; n < 4; ++n) acc[m][n] = z4;

  // read offsets: byte within 128B row, swizzled; per-lane constant
  const int xo0 = (l4 * 16) ^ ((l15 & 7) << 4);
  const int xo1 = (64 + l4 * 16) ^ ((l15 & 7) << 4);
  const char* aRd = (const char*)&As[0][0] + (wm * 64 + l15) * 128;
  const char* bRd = (const char*)&Bs[0][0] + (wn * 32 + l15) * 128;

  // prologue: issue A(0), Bh0(0), Bh1(0)  [6 loads]
  GLL16(aSrc0, &As[0][ldsA]);
  GLL16(aSrc1, &As[0][ldsA + 512]);
  GLL16(bSrc0, &Bs[0][ldsA]);
  GLL16(bSrc1, &Bs[0][ldsA + 512]);
  GLL16(bSrc0 + bHS, &Bs[0][8192 + ldsA]);
  GLL16(bSrc1 + bHS, &Bs[0][8192 + ldsA + 512]);

  short8 af[4][2], bf[4][2];

  for (int t = 0; t < NT; ++t) {
    const int nxt = t + 1;
    const int bufo = t & 1;

    // ---- phase 0: stage A(t+1)+Bh0(t+1); compute n-cols 0..1 ----
    if (nxt < NT) {
      const long ko = (long)nxt * 64;
      const int nb = nxt & 1;
      GLL16(aSrc0 + ko, &As[nb][ldsA]);
      GLL16(aSrc1 + ko, &As[nb][ldsA + 512]);
      GLL16(bSrc0 + ko, &Bs[nb][ldsA]);
      GLL16(bSrc1 + ko, &Bs[nb][ldsA + 512]);
      asm volatile("s_waitcnt vmcnt(6)\ns_barrier" ::: "memory");
    } else {
      asm volatile("s_waitcnt vmcnt(2)\ns_barrier" ::: "memory");
    }
    const char* ab = aRd + bufo * 16384;
    const char* bb = bRd + bufo * 32768;
    #pragma unroll
    for (int m = 0; m < 4; ++m) {
      af[m][0] = *(const short8*)(ab + m * 2048 + xo0);
      af[m][1] = *(const short8*)(ab + m * 2048 + xo1);
    }
    #pragma unroll
    for (int n = 0; n < 2; ++n) {
      bf[n][0] = *(const short8*)(bb + n * 2048 + xo0);
      bf[n][1] = *(const short8*)(bb + n * 2048 + xo1);
    }
    __builtin_amdgcn_s_setprio(1);
    #pragma unroll
    for (int m = 0; m < 4; ++m)
      #pragma unroll
      for (int n = 0; n < 2; ++n) {
        acc[m][n] = MFMA16x16x32(af[m][0], bf[n][0], acc[m][n]);
        acc[m][n] = MFMA16x16x32(af[m][1], bf[n][1], acc[m][n]);
      }
    __builtin_amdgcn_s_setprio(0);

    // ---- phase 1: stage Bh1(t+1); compute n-cols 2..3 ----
    if (nxt < NT) {
      const long ko = (long)nxt * 64;
      const int nb = nxt & 1;
      GLL16(bSrc0 + bHS + ko, &Bs[nb][8192 + ldsA]);
      GLL16(bSrc1 + bHS + ko, &Bs[nb][8192 + ldsA + 512]);
      asm volatile("s_waitcnt vmcnt(6)\ns_barrier" ::: "memory");
    } else {
      asm volatile("s_waitcnt vmcnt(0)\ns_barrier" ::: "memory");
    }
    const char* bb1 = bb + 16384;
    #pragma unroll
    for (int n = 0; n < 2; ++n) {
      bf[2 + n][0] = *(const short8*)(bb1 + n * 2048 + xo0);
      bf[2 + n][1] = *(const short8*)(bb1 + n * 2048 + xo1);
    }
    __builtin_amdgcn_s_setprio(1);
    #pragma unroll
    for (int m = 0; m < 4; ++m)
      #pragma unroll
      for (int n = 2; n < 4; ++n) {
        acc[m][n] = MFMA16x16x32(af[m][0], bf[n][0], acc[m][n]);
        acc[m][n] = MFMA16x16x32(af[m][1], bf[n][1], acc[m][n]);
      }
    __builtin_amdgcn_s_setprio(0);
  }

  // ---- epilogue ----
  #pragma unroll
  for (int m = 0; m < 4; ++m) {
    const long row0 = bm + wm * 64 + m * 16 + l4 * 4;
    #pragma unroll
    for (int n = 0; n < 4; ++n) {
      const long col = bn + wn * 32 + (n & 1) * 16 + (n >> 1) * 128 + l15;
      const float bv = bias[col];
      #pragma unroll
      for (int r = 0; r < 4; ++r) {
        const float v = acc[m][n][r] + bv;
        if (OUT_BF16)
          ((u16*)C)[(row0 + r) * (long)N + col] = f32_to_bf16(v);
        else
          ((float*)C)[(row0 + r) * (long)N + col] = v;
      }
    }
  }
}

// ---------------- repack K and V into per-tile LDS images ----------------
__global__ __launch_bounds__(256) void repack_kv(
    const u16* __restrict__ qkv, u16* __restrict__ kimg, u16* __restrict__ vimg)
{
  const int t = blockIdx.x;  // kv tile 0..31
  const int h = blockIdx.y, b = blockIdx.z;
  const int tid = threadIdx.x;
  __shared__ u16 Vl[64][136];

  const long qbase = ((long)(b * 2048 + t * 64)) * 6144 + h * 128;
  u16* kout = kimg + (((long)(b * 16 + h) * 32 + t) * 8192);
  u16* vout = vimg + (((long)(b * 16 + h) * 32 + t) * 8192);

  #pragma unroll
  for (int i = 0; i < 4; ++i) {
    const int j = tid + i * 256;
    {
      const int r = j >> 4, c8 = (j & 15) * 8;
      uint4 v = *(const uint4*)(qkv + qbase + (long)r * 6144 + 4096 + c8);
      *(uint4*)(&Vl[r][c8]) = v;
    }
    {
      const int byte = j * 16;
      const int r = byte >> 8;
      const int wv = (byte & 255) ^ ((r & 7) << 4);
      const int d0 = wv >> 1;
      uint4 v = *(const uint4*)(qkv + qbase + (long)r * 6144 + 2048 + d0);
      *(uint4*)(kout + j * 8) = v;
    }
  }
  __syncthreads();
  #pragma unroll
  for (int i = 0; i < 4; ++i) {
    const int j = tid + i * 256;
    const int byte = j * 16;
    const int d = byte >> 7;
    const int wv = (byte & 127) ^ ((d & 7) << 4);
    const int k0 = wv >> 1;
    u16 tmp[8];
    #pragma unroll
    for (int m = 0; m < 8; ++m) tmp[m] = Vl[k0 + m][d];
    *(uint4*)(vout + j * 8) = *(const uint4*)tmp;
  }
}

// ---------------- flash causal attention with alibi ----------------
__global__ __launch_bounds__(256) void attn_kernel(
    const u16* __restrict__ qkv,   // [B*S][6144] bf16
    const u16* __restrict__ kimg,  // [B][H][32][8192] tile images
    const u16* __restrict__ vimg,
    u16* __restrict__ ctx)         // [B*S][2048] bf16
{
  const int S = 2048, NHD = 6144, NT = 32;
  const int p = blockIdx.x, h = blockIdx.y, b = blockIdx.z;
  const int tid = threadIdx.x;
  const int w = tid >> 6, l = tid & 63;
  const int l15 = l & 15, l4 = l >> 4;

  __shared__ u16 Ks[64 * 128];
  __shared__ u16 Vt[128 * 64];
  __shared__ u16 Ps[4][16 * 64];

  const float LOG2E = 1.44269504088896f;
  const float c1 = 0.08838834764831845f * LOG2E;
  const float slope2 = exp2f(-0.5f * (float)(h + 1)) * LOG2E;

  const f32x4 z4 = {0.f, 0.f, 0.f, 0.f};

  for (int pass = 0; pass < 2; ++pass) {
    const int qblk = pass ? (NT - 1 - p) : p;
    const int qb0 = qblk * 64;

    short8 qf[4];
    {
      const int qrow = qb0 + w * 16 + l15;
      const u16* qp = qkv + (long)(b * S + qrow) * NHD + h * 128 + l4 * 8;
      #pragma unroll
      for (int kc = 0; kc < 4; ++kc) qf[kc] = *(const short8*)(qp + kc * 32);
    }

    f32x4 o[8];
    #pragma unroll
    for (int i = 0; i < 8; ++i) o[i] = z4;
    float m_r[4] = {-3.0e38f, -3.0e38f, -3.0e38f, -3.0e38f};
    float l_r[4] = {0.f, 0.f, 0.f, 0.f};

    for (int kt = 0; kt <= qblk; ++kt) {
      const u16* ksrc = kimg + (((long)(b * 16 + h) * NT + kt) * 8192);
      const u16* vsrc = vimg + (((long)(b * 16 + h) * NT + kt) * 8192);
      #pragma unroll
      for (int i = 0; i < 4; ++i) {
        const int chunk = w * 4 + i;
        __builtin_amdgcn_global_load_lds(
            (const __attribute__((address_space(1))) void*)(ksrc + chunk * 512 + l * 8),
            (__attribute__((address_space(3))) void*)(Ks + chunk * 512), 16, 0, 0);
        __builtin_amdgcn_global_load_lds(
            (const __attribute__((address_space(1))) void*)(vsrc + chunk * 512 + l * 8),
            (__attribute__((address_space(3))) void*)(Vt + chunk * 512), 16, 0, 0);
      }
      __syncthreads();

      f32x4 sf[4];
      #pragma unroll
      for (int nt = 0; nt < 4; ++nt) sf[nt] = z4;
      #pragma unroll
      for (int nt = 0; nt < 4; ++nt) {
        const int krow = nt * 16 + l15;
        #pragma unroll
        for (int kc = 0; kc < 4; ++kc) {
          int kbyte = (krow * 256 + kc * 64 + l4 * 16) ^ ((krow & 7) << 4);
          const short8 kf = *(const short8*)((const char*)Ks + kbyte);
          sf[nt] = MFMA16x16x32(qf[kc], kf, sf[nt]);
        }
      }

      float add_nt[4];
      int kg_nt[4];
      #pragma unroll
      for (int nt = 0; nt < 4; ++nt) {
        kg_nt[nt] = kt * 64 + nt * 16 + l15;
        add_nt[nt] = slope2 * (float)(kg_nt[nt] - (S - 1));
      }
      const bool diag = (kt == qblk);
      float alpha[4];
      #pragma unroll
      for (int r = 0; r < 4; ++r) {
        const int qrow_l = l4 * 4 + r;
        const int qg = qb0 + w * 16 + qrow_l;
        float sc[4];
        #pragma unroll
        for (int nt = 0; nt < 4; ++nt) sc[nt] = sf[nt][r] * c1 + add_nt[nt];
        if (diag) {
          #pragma unroll
          for (int nt = 0; nt < 4; ++nt)
            if (kg_nt[nt] > qg) sc[nt] = -3.0e38f;
        }
        float mx = fmaxf(fmaxf(sc[0], sc[1]), fmaxf(sc[2], sc[3]));
        #pragma unroll
        for (int d = 1; d < 16; d <<= 1) mx = fmaxf(mx, __shfl_xor(mx, d, 64));
        const float mnew = fmaxf(m_r[r], mx);
        float sum = 0.f;
        #pragma unroll
        for (int nt = 0; nt < 4; ++nt) {
          const float pv = exp2f(sc[nt] - mnew);
          sc[nt] = pv;
          sum += pv;
        }
        #pragma unroll
        for (int d = 1; d < 16; d <<= 1) sum += __shfl_xor(sum, d, 64);
        alpha[r] = exp2f(m_r[r] - mnew);
        l_r[r] = l_r[r] * alpha[r] + sum;
        m_r[r] = mnew;
        #pragma unroll
        for (int nt = 0; nt < 4; ++nt) {
          int pbyte = ((qrow_l * 64 + nt * 16 + l15) * 2) ^ ((qrow_l & 7) << 4);
          *(u16*)((char*)&Ps[w][0] + pbyte) = f32_to_bf16(sc[nt]);
        }
      }

      #pragma unroll
      for (int nt = 0; nt < 8; ++nt)
        #pragma unroll
        for (int r = 0; r < 4; ++r) o[nt][r] *= alpha[r];

      #pragma unroll
      for (int kc = 0; kc < 2; ++kc) {
        int pbyte = ((l15 * 64 + kc * 32 + l4 * 8) * 2) ^ ((l15 & 7) << 4);
        const short8 pf = *(const short8*)((const char*)&Ps[w][0] + pbyte);
        #pragma unroll
        for (int nt = 0; nt < 8; ++nt) {
          const int d = nt * 16 + l15;
          const int vbyte = ((d * 128 + kc * 64 + l4 * 16)) ^ ((d & 7) << 4);
          const short8 vf = *(const short8*)((const char*)Vt + vbyte);
          o[nt] = MFMA16x16x32(pf, vf, o[nt]);
        }
      }
      __syncthreads();
    }

    float rl[4];
    #pragma unroll
    for (int r = 0; r < 4; ++r) rl[r] = 1.0f / l_r[r];
    #pragma unroll
    for (int nt = 0; nt < 8; ++nt) {
      #pragma unroll
      for (int r = 0; r < 4; ++r) {
        const int qg = qb0 + w * 16 + l4 * 4 + r;
        ctx[(long)(b * S + qg) * 2048 + h * 128 + nt * 16 + l15] =
            f32_to_bf16(o[nt][r] * rl[r]);
      }
    }
  }
}

// ---------------- launch ----------------
extern "C" void kernel_launch(void* const* d_in, const int* in_sizes, int n_in,
                              void* d_out, int out_size, void* d_ws, size_t ws_size,
                              hipStream_t stream) {
  const float* x     = (const float*)d_in[0];
  const float* w_qkv = (const float*)d_in[2];
  const float* b_qkv = (const float*)d_in[3];
  const float* w_out = (const float*)d_in[4];
  const float* b_out = (const float*)d_in[5];
  float* out = (float*)d_out;

  // B=2, S=2048, D=2048, H=16, hd=128
  char* ws = (char*)d_ws;
  u16* xb    = (u16*)(ws);                     // 4096x2048   (16.8 MB) dead after GEMM1
  u16* wqkvb = (u16*)(ws + 16777216UL);        // 6144x2048   (25.2 MB) dead after GEMM1
  u16* woutb = (u16*)(ws + 41943040UL);        // 2048x2048   ( 8.4 MB)
  u16* qkvb  = (u16*)(ws + 50331648UL);        // 4096x6144   (50.3 MB)
  u16* ctxb  = (u16*)(ws + 100663296UL);       // 4096x2048   (16.8 MB)
  u16* kimg  = (u16*)(ws);                     // 16.8 MB (overlays xb)
  u16* vimg  = (u16*)(ws + 16777216UL);        // 16.8 MB (overlays wqkvb)

  cvt_f32_bf16<<<2048, 256, 0, stream>>>(x, xb, 8388608 / 4);
  cvt_f32_bf16<<<2048, 256, 0, stream>>>(w_qkv, wqkvb, 12582912 / 4);
  cvt_f32_bf16<<<2048, 256, 0, stream>>>(w_out, woutb, 4194304 / 4);

  gemm_nt_8p<1><<<dim3(24, 32), 512, 0, stream>>>(xb, wqkvb, b_qkv, (void*)qkvb, 4096, 6144, 2048);

  repack_kv<<<dim3(32, 16, 2), 256, 0, stream>>>(qkvb, kimg, vimg);

  attn_kernel<<<dim3(16, 16, 2), 256, 0, stream>>>(qkvb, kimg, vimg, ctxb);

  gemm_nt_8p<0><<<dim3(8, 32), 512, 0, stream>>>(ctxb, woutb, b_out, (void*)out, 4096, 2048, 2048);
}